// Round 1
// baseline (1272.185 us; speedup 1.0000x reference)
//
#include <hip/hip_runtime.h>
#include <hip/hip_bf16.h>
#include <math.h>

typedef __attribute__((ext_vector_type(4))) float f32x4;
typedef __attribute__((ext_vector_type(8))) short bf16x8;

__device__ __forceinline__ unsigned short f2bf(float f) {
  unsigned int x = __builtin_bit_cast(unsigned int, f);
  x += 0x7fffu + ((x >> 16) & 1u);
  return (unsigned short)(x >> 16);
}

__device__ __forceinline__ void gload_lds16(const void* g, void* l) {
  __builtin_amdgcn_global_load_lds(
      (const __attribute__((address_space(1))) unsigned int*)g,
      (__attribute__((address_space(3))) unsigned int*)l, 16, 0, 0);
}

// ---------------- f32 -> bf16 cast ----------------
__global__ void cvt_f32_bf16(const float* __restrict__ s, unsigned short* __restrict__ d, int n) {
  int i = blockIdx.x * 256 + threadIdx.x;
  if (i < n) d[i] = f2bf(s[i]);
}

// ---------------- LayerNorm (optionally with shift+window gather) ----------------
// REMAP=1: r is a window-order row; gather from image position ((wi*8+i+4)&127, (wj*8+j+4)&127)
template <int REMAP>
__global__ __launch_bounds__(256)
void ln_kernel(const float* __restrict__ x, const float* __restrict__ g,
               const float* __restrict__ b, unsigned short* __restrict__ dst_o) {
  int r = blockIdx.x * 4 + (threadIdx.x >> 6);
  int lane = threadIdx.x & 63;
  size_t src;
  if (REMAP) {
    int w = r >> 6, t = r & 63;
    int bb = w >> 8, wi = (w >> 4) & 15, wj = w & 15;
    int i = t >> 3, j = t & 7;
    int p = (wi * 8 + i + 4) & 127, q = (wj * 8 + j + 4) & 127;
    src = ((size_t)bb * 16384 + p * 128 + q) * 384;
  } else {
    src = (size_t)r * 384;
  }
  float v[6];
  float s = 0.f, s2 = 0.f;
#pragma unroll
  for (int m = 0; m < 6; ++m) {
    v[m] = x[src + lane + 64 * m];
    s += v[m];
    s2 += v[m] * v[m];
  }
#pragma unroll
  for (int o2 = 1; o2 < 64; o2 <<= 1) {
    s += __shfl_xor(s, o2);
    s2 += __shfl_xor(s2, o2);
  }
  float mu = s * (1.f / 384.f);
  float var = s2 * (1.f / 384.f) - mu * mu;
  float ri = rsqrtf(var + 1e-5f);
  size_t dst = (size_t)r * 384;
#pragma unroll
  for (int m = 0; m < 6; ++m) {
    int c = lane + 64 * m;
    dst_o[dst + c] = f2bf((v[m] - mu) * ri * g[c] + b[c]);
  }
}

// ---------------- GEMM: C(M,N) = A(M,K) * B(N,K)^T  (both bf16 row-major, K-major) ----------------
// EPI 0: out = bf16(acc + bias)                       -> Obf
// EPI 1: out = bf16(gelu(acc + bias))                 -> Obf
// EPI 2: proj: scatter window->image, += resid(x)     -> Of (f32)
// EPI 3: out = acc + bias + resid                     -> Of (f32)
template <int EPI>
__global__ __launch_bounds__(256, 2)
void gemm_bt(const unsigned short* __restrict__ A, const unsigned short* __restrict__ Bw,
             const float* __restrict__ bias, int M, int N, int K,
             unsigned short* __restrict__ Obf, const float* __restrict__ resid,
             float* __restrict__ Of) {
  __shared__ unsigned short smA[128 * 64];
  __shared__ unsigned short smB[128 * 64];
  const int tid = threadIdx.x;
  const int lane = tid & 63;
  const int wid = tid >> 6;
  const int wm = wid >> 1, wn = wid & 1;
  const int li = lane & 15, lg = lane >> 4;
  const int m0 = blockIdx.y * 128;
  const int n0 = blockIdx.x * 128;

  f32x4 acc[4][4] = {};

  const int srow = wid * 32 + (lane >> 3);  // staging row for this lane (within tile)
  const int scol = (lane & 7) * 8;          // staging col in elements (16B per lane)
  const unsigned short* gA = A + (size_t)(m0 + srow) * K + scol;
  const unsigned short* gB = Bw + (size_t)(n0 + srow) * K + scol;

  for (int k0 = 0; k0 < K; k0 += 64) {
#pragma unroll
    for (int c = 0; c < 4; ++c) {
      gload_lds16(gA + (size_t)(c * 8) * K + k0, &smA[(wid * 32 + c * 8) * 64]);
      gload_lds16(gB + (size_t)(c * 8) * K + k0, &smB[(wid * 32 + c * 8) * 64]);
    }
    __syncthreads();
#pragma unroll
    for (int kk = 0; kk < 2; ++kk) {
      bf16x8 a[4], bb[4];
#pragma unroll
      for (int f = 0; f < 4; ++f) {
        a[f] = *(const bf16x8*)&smA[(wm * 64 + f * 16 + li) * 64 + kk * 32 + lg * 8];
        bb[f] = *(const bf16x8*)&smB[(wn * 64 + f * 16 + li) * 64 + kk * 32 + lg * 8];
      }
#pragma unroll
      for (int mf = 0; mf < 4; ++mf)
#pragma unroll
        for (int nf = 0; nf < 4; ++nf)
          acc[mf][nf] = __builtin_amdgcn_mfma_f32_16x16x32_bf16(a[mf], bb[nf], acc[mf][nf], 0, 0, 0);
    }
    __syncthreads();
  }

  // epilogue: C/D layout col = lane&15, row = (lane>>4)*4 + reg
#pragma unroll
  for (int mf = 0; mf < 4; ++mf) {
#pragma unroll
    for (int r = 0; r < 4; ++r) {
      int mrow = m0 + wm * 64 + mf * 16 + lg * 4 + r;
      size_t orow = (size_t)mrow;
      if (EPI == 2) {
        int w = mrow >> 6, t = mrow & 63;
        int bb2 = w >> 8, wi = (w >> 4) & 15, wj = w & 15;
        int i = t >> 3, j = t & 7;
        int p = (wi * 8 + i + 4) & 127, q = (wj * 8 + j + 4) & 127;
        orow = (size_t)bb2 * 16384 + p * 128 + q;
      }
#pragma unroll
      for (int nf = 0; nf < 4; ++nf) {
        int col = n0 + wn * 64 + nf * 16 + li;
        float v = acc[mf][nf][r] + bias[col];
        if (EPI == 0) {
          Obf[(size_t)mrow * N + col] = f2bf(v);
        } else if (EPI == 1) {
          float gl = 0.5f * v * (1.f + erff(v * 0.70710678118654752f));
          Obf[(size_t)mrow * N + col] = f2bf(gl);
        } else if (EPI == 2) {
          Of[orow * 384 + col] = v + resid[orow * 384 + col];
        } else {
          Of[(size_t)mrow * N + col] = v + resid[(size_t)mrow * N + col];
        }
      }
    }
  }
}

// ---------------- windowed attention: one block per window, 4 waves x 3 heads ----------------
__global__ __launch_bounds__(256, 2)
void attn_kernel(const unsigned short* __restrict__ qkv, const float* __restrict__ btab,
                 const float* __restrict__ mask, unsigned short* __restrict__ out) {
  __shared__ unsigned short v_lds[4][64 * 40];  // V tile, row stride 40
  __shared__ unsigned short p_lds[4][64 * 72];  // P tile, row stride 72
  const int w = blockIdx.x;
  const int tid = threadIdx.x;
  const int wid = tid >> 6, lane = tid & 63;
  const int li = lane & 15, lg = lane >> 4;
  const float* mrow = mask + (size_t)(w & 255) * 4096;
  const size_t base = (size_t)w * 64;
  const float SC = 0.17677669529663688f;  // 32^-0.5

#pragma unroll 1
  for (int hi = 0; hi < 3; ++hi) {
    int h = wid * 3 + hi;
    // Q (A-frag) and K (B-frag) straight from global: row = token, 8 contiguous hd elems
    bf16x8 aq[4], bk[4];
#pragma unroll
    for (int f = 0; f < 4; ++f) {
      size_t off = (base + f * 16 + li) * 1152 + h * 32 + lg * 8;
      aq[f] = *(const bf16x8*)&qkv[off];
      bk[f] = *(const bf16x8*)&qkv[off + 384];
    }
    f32x4 s[4][4] = {};
#pragma unroll
    for (int mf = 0; mf < 4; ++mf)
#pragma unroll
      for (int nf = 0; nf < 4; ++nf)
        s[mf][nf] = __builtin_amdgcn_mfma_f32_16x16x32_bf16(aq[mf], bk[nf], s[mf][nf], 0, 0, 0);

    // stage V tile (this wave's head): lane -> one row of 32 bf16
    {
      const unsigned short* vp = &qkv[(base + lane) * 1152 + 768 + h * 32];
      unsigned short* dp = &v_lds[wid][lane * 40];
#pragma unroll
      for (int c = 0; c < 4; ++c) *(bf16x8*)&dp[c * 8] = *(const bf16x8*)&vp[c * 8];
    }

    // scale + rel-pos bias + shift mask + softmax over n (cols)
#pragma unroll
    for (int mf = 0; mf < 4; ++mf) {
#pragma unroll
      for (int r = 0; r < 4; ++r) {
        int m = mf * 16 + lg * 4 + r;
        float mx = -1e30f;
#pragma unroll
        for (int nf = 0; nf < 4; ++nf) {
          int n = nf * 16 + li;
          int ridx = ((m >> 3) - (n >> 3) + 7) * 15 + (m & 7) - (n & 7) + 7;
          float val = s[mf][nf][r] * SC + btab[ridx * 12 + h] + mrow[m * 64 + n];
          s[mf][nf][r] = val;
          mx = fmaxf(mx, val);
        }
#pragma unroll
        for (int o2 = 1; o2 < 16; o2 <<= 1) mx = fmaxf(mx, __shfl_xor(mx, o2));
        float sum = 0.f;
#pragma unroll
        for (int nf = 0; nf < 4; ++nf) {
          float e = __expf(s[mf][nf][r] - mx);
          s[mf][nf][r] = e;
          sum += e;
        }
#pragma unroll
        for (int o2 = 1; o2 < 16; o2 <<= 1) sum += __shfl_xor(sum, o2);
        float inv = 1.f / sum;
#pragma unroll
        for (int nf = 0; nf < 4; ++nf) s[mf][nf][r] *= inv;
      }
    }

    // P -> LDS (bf16), D layout -> absolute [m][n]
#pragma unroll
    for (int mf = 0; mf < 4; ++mf)
#pragma unroll
      for (int nf = 0; nf < 4; ++nf)
#pragma unroll
        for (int r = 0; r < 4; ++r) {
          int m = mf * 16 + lg * 4 + r, n = nf * 16 + li;
          p_lds[wid][m * 72 + n] = f2bf(s[mf][nf][r]);
        }

    // PV: out[m][d] = sum_n P[m][n] V[n][d]
    f32x4 o[4][2] = {};
#pragma unroll
    for (int kf = 0; kf < 2; ++kf) {
      bf16x8 bv[2];
#pragma unroll
      for (int df = 0; df < 2; ++df) {
        bf16x8 t;
#pragma unroll
        for (int e = 0; e < 8; ++e)
          t[e] = (short)v_lds[wid][(kf * 32 + lg * 8 + e) * 40 + df * 16 + li];
        bv[df] = t;
      }
#pragma unroll
      for (int mf = 0; mf < 4; ++mf) {
        bf16x8 pa = *(const bf16x8*)&p_lds[wid][(mf * 16 + li) * 72 + kf * 32 + lg * 8];
#pragma unroll
        for (int df = 0; df < 2; ++df)
          o[mf][df] = __builtin_amdgcn_mfma_f32_16x16x32_bf16(pa, bv[df], o[mf][df], 0, 0, 0);
      }
    }

    // store attn_out[token][h*32 + d] (window order)
#pragma unroll
    for (int mf = 0; mf < 4; ++mf)
#pragma unroll
      for (int df = 0; df < 2; ++df)
#pragma unroll
        for (int r = 0; r < 4; ++r) {
          size_t row = base + mf * 16 + lg * 4 + r;
          out[row * 384 + h * 32 + df * 16 + li] = f2bf(o[mf][df][r]);
        }
  }
}

extern "C" void kernel_launch(void* const* d_in, const int* in_sizes, int n_in,
                              void* d_out, int out_size, void* d_ws, size_t ws_size,
                              hipStream_t stream) {
  const float* x      = (const float*)d_in[0];
  const float* qkv_w  = (const float*)d_in[1];
  const float* qkv_b  = (const float*)d_in[2];
  const float* proj_w = (const float*)d_in[3];
  const float* proj_b = (const float*)d_in[4];
  const float* rel    = (const float*)d_in[5];
  const float* g1     = (const float*)d_in[6];
  const float* b1     = (const float*)d_in[7];
  const float* g2     = (const float*)d_in[8];
  const float* b2     = (const float*)d_in[9];
  const float* fc1_w  = (const float*)d_in[10];
  const float* fc1_b  = (const float*)d_in[11];
  const float* fc2_w  = (const float*)d_in[12];
  const float* fc2_b  = (const float*)d_in[13];
  const float* mask   = (const float*)d_in[14];
  float* out = (float*)d_out;
  char* ws = (char*)d_ws;

  const int M = 131072;  // B * H * W tokens
  // workspace layout (lifetime-overlapped):
  //   [0, 402653184): hw bf16 (100663296 B) + qkv bf16 (301989888 B); later reused as hmid bf16
  //   [402653184, +100663296): attn_out bf16; later reused as ln2 bf16
  //   [503316480, +201326592): x1 f32
  //   [704643072, +3538944):   bf16 weights
  unsigned short* hw     = (unsigned short*)ws;
  unsigned short* qkv    = (unsigned short*)(ws + 100663296);
  unsigned short* hmid   = (unsigned short*)ws;
  unsigned short* attn_o = (unsigned short*)(ws + 402653184);
  unsigned short* ln2o   = attn_o;
  float*          x1     = (float*)(ws + 503316480);
  unsigned short* wq     = (unsigned short*)(ws + 704643072);
  unsigned short* wp     = wq + 442368;
  unsigned short* w1     = wp + 147456;
  unsigned short* w2     = w1 + 589824;

  // weight casts
  cvt_f32_bf16<<<(442368 + 255) / 256, 256, 0, stream>>>(qkv_w, wq, 442368);
  cvt_f32_bf16<<<(147456 + 255) / 256, 256, 0, stream>>>(proj_w, wp, 147456);
  cvt_f32_bf16<<<(589824 + 255) / 256, 256, 0, stream>>>(fc1_w, w1, 589824);
  cvt_f32_bf16<<<(589824 + 255) / 256, 256, 0, stream>>>(fc2_w, w2, 589824);

  // LN1 + shift + window partition
  ln_kernel<1><<<M / 4, 256, 0, stream>>>(x, g1, b1, hw);

  // QKV projection
  gemm_bt<0><<<dim3(9, 1024), 256, 0, stream>>>(hw, wq, qkv_b, M, 1152, 384, qkv, nullptr, nullptr);

  // windowed attention
  attn_kernel<<<2048, 256, 0, stream>>>(qkv, rel, mask, attn_o);

  // proj + window reverse + unshift + residual -> x1
  gemm_bt<2><<<dim3(3, 1024), 256, 0, stream>>>(attn_o, wp, proj_b, M, 384, 384, nullptr, x, x1);

  // LN2
  ln_kernel<0><<<M / 4, 256, 0, stream>>>(x1, g2, b2, ln2o);

  // FC1 + GELU
  gemm_bt<1><<<dim3(12, 1024), 256, 0, stream>>>(ln2o, w1, fc1_b, M, 1536, 384, hmid, nullptr, nullptr);

  // FC2 + residual -> out
  gemm_bt<3><<<dim3(3, 1024), 256, 0, stream>>>(hmid, w2, fc2_b, M, 384, 1536, nullptr, x1, out);
}